// Round 6
// baseline (891.350 us; speedup 1.0000x reference)
//
#include <hip/hip_runtime.h>
#include <hip/hip_bf16.h>
#include <math.h>

#define NNODES 20000
#define NEDGES 640000
#define BSZ 256
#define GDIM 256
#define HID 512
#define INNER 2048
#define RANK 512
#define NCLS 3
#define NGENES 6640

typedef __attribute__((ext_vector_type(8))) short bf16x8;
typedef __attribute__((ext_vector_type(4))) float f32x4;

__device__ inline float bf2f(unsigned short u) {
    return __uint_as_float(((unsigned)u) << 16);
}
__device__ inline unsigned short f2bf(float f) {
    unsigned u = __float_as_uint(f);
    u = u + 0x7fff + ((u >> 16) & 1);   // RNE
    return (unsigned short)(u >> 16);
}

// ---------------- CSR build ----------------
__global__ void hist_k(const int* __restrict__ dst, int* __restrict__ counts, int E) {
    int e = blockIdx.x * 256 + threadIdx.x;
    if (e < E) atomicAdd(&counts[dst[e]], 1);
}

// single-block scan over counts -> row_start/cursor (n <= 20480)
__global__ __launch_bounds__(1024) void scanall_k(const int* __restrict__ counts,
                                                  int* __restrict__ row_start,
                                                  int* __restrict__ cursor, int n) {
    __shared__ int tsum[1024];
    int t = threadIdx.x;
    int base = t * 20;
    int s = 0;
#pragma unroll 4
    for (int i = 0; i < 20; i++) {
        int idx = base + i;
        s += (idx < n) ? counts[idx] : 0;
    }
    tsum[t] = s;
    __syncthreads();
    for (int off = 1; off < 1024; off <<= 1) {
        int v = (t >= off) ? tsum[t - off] : 0;
        __syncthreads();
        tsum[t] += v;
        __syncthreads();
    }
    int run = (t == 0) ? 0 : tsum[t - 1];
    for (int i = 0; i < 20; i++) {
        int idx = base + i;
        if (idx < n) {
            row_start[idx] = run;
            cursor[idx] = run;
            run += counts[idx];
        }
    }
}

__global__ void scatter_k(const int* __restrict__ src, const int* __restrict__ dst,
                          const float* __restrict__ w, int* __restrict__ cursor,
                          int2* __restrict__ ep, int E) {
    int e = blockIdx.x * 256 + threadIdx.x;
    if (e < E) {
        int d = dst[e];
        int p = atomicAdd(&cursor[d], 1);
        ep[p] = make_int2(src[e], __float_as_int(w[e]));
    }
}

// ---------------- mega conversion kernel: all weight transposes + gene cast ----------------
// segments (tile counts at 32x32): gnn 192 | post 64 | pin 128 | w1 6144 | w2 6144 | pout 768 |
// gene elementwise 1660 blocks. total 15100.
__global__ void convall_k(const float* __restrict__ gnn_w, const float* __restrict__ post_w,
                          const float* __restrict__ pin_w, const float* __restrict__ blk_w1,
                          const float* __restrict__ blk_w2, const float* __restrict__ pout_w,
                          const float* __restrict__ gene, unsigned short* __restrict__ gnnT,
                          unsigned short* __restrict__ postT, unsigned short* __restrict__ pinT,
                          unsigned short* __restrict__ w1T, unsigned short* __restrict__ w2T,
                          unsigned short* __restrict__ poutT,
                          unsigned short* __restrict__ geneb) {
    __shared__ float s[32][33];
    int bid = blockIdx.x;
    int tx = threadIdx.x, ty = threadIdx.y;
    const float* W;
    unsigned short* WT;
    int K, N, k0, n0;
    if (bid < 192) {
        int l = bid >> 6, rem = bid & 63;
        W = gnn_w + (size_t)l * GDIM * GDIM;
        WT = gnnT + (size_t)l * GDIM * GDIM;
        K = GDIM; N = GDIM;
        n0 = (rem & 7) * 32; k0 = (rem >> 3) * 32;
    } else if (bid < 256) {
        int rem = bid - 192;
        W = post_w; WT = postT; K = GDIM; N = GDIM;
        n0 = (rem & 7) * 32; k0 = (rem >> 3) * 32;
    } else if (bid < 384) {
        int rem = bid - 256;
        W = pin_w; WT = pinT; K = GDIM; N = HID;
        n0 = (rem & 15) * 32; k0 = (rem >> 4) * 32;
    } else if (bid < 6528) {
        int rem = bid - 384;
        int l = rem >> 10; rem &= 1023;
        W = blk_w1 + (size_t)l * HID * INNER;
        WT = w1T + (size_t)l * HID * INNER;
        K = HID; N = INNER;
        n0 = (rem & 63) * 32; k0 = (rem >> 6) * 32;
    } else if (bid < 12672) {
        int rem = bid - 6528;
        int l = rem >> 10; rem &= 1023;
        W = blk_w2 + (size_t)l * INNER * HID;
        WT = w2T + (size_t)l * INNER * HID;
        K = INNER; N = HID;
        n0 = (rem & 15) * 32; k0 = (rem >> 4) * 32;
    } else if (bid < 13440) {
        int rem = bid - 12672;
        W = pout_w; WT = poutT; K = HID; N = NCLS * RANK;
        n0 = (rem % 48) * 32; k0 = (rem / 48) * 32;
    } else {
        // gene: elementwise fp32 -> bf16, 8 elems per thread
        int i8 = (bid - 13440) * 256 + ty * 32 + tx;
        const float4* xp = (const float4*)gene;
        float4 a = xp[i8 * 2], b = xp[i8 * 2 + 1];
        *(ushort4*)(geneb + (size_t)i8 * 8) =
            make_ushort4(f2bf(a.x), f2bf(a.y), f2bf(a.z), f2bf(a.w));
        *(ushort4*)(geneb + (size_t)i8 * 8 + 4) =
            make_ushort4(f2bf(b.x), f2bf(b.y), f2bf(b.z), f2bf(b.w));
        return;
    }
#pragma unroll
    for (int i = 0; i < 4; i++)
        s[ty + 8 * i][tx] = W[(size_t)(k0 + ty + 8 * i) * N + n0 + tx];
    __syncthreads();
#pragma unroll
    for (int i = 0; i < 4; i++)
        WT[(size_t)(n0 + ty + 8 * i) * K + k0 + tx] = f2bf(s[tx][ty + 8 * i]);
}

// ---------------- GNN LayerNorm (D=256), bf16 out (layer-1 input only) ----------------
__global__ void lnb_k(const float* __restrict__ X, const float* __restrict__ sc,
                      const float* __restrict__ bi, unsigned short* __restrict__ Y, int M) {
    int row = blockIdx.x * 4 + (threadIdx.x >> 6);
    int lane = threadIdx.x & 63;
    if (row >= M) return;
    float4 v = ((const float4*)(X + (size_t)row * GDIM))[lane];
    float sum = v.x + v.y + v.z + v.w;
#pragma unroll
    for (int off = 32; off >= 1; off >>= 1) sum += __shfl_xor(sum, off);
    float mu = sum / GDIM;
    float a = v.x - mu, b = v.y - mu, c = v.z - mu, d = v.w - mu;
    float sq = a * a + b * b + c * c + d * d;
#pragma unroll
    for (int off = 32; off >= 1; off >>= 1) sq += __shfl_xor(sq, off);
    float rstd = rsqrtf(sq / GDIM + 1e-5f);
    float4 s4 = ((const float4*)sc)[lane];
    float4 b4 = ((const float4*)bi)[lane];
    *(ushort4*)(Y + (size_t)row * GDIM + lane * 4) =
        make_ushort4(f2bf(a * rstd * s4.x + b4.x), f2bf(b * rstd * s4.y + b4.y),
                     f2bf(c * rstd * s4.z + b4.z), f2bf(d * rstd * s4.w + b4.w));
}

// ---------------- CSR aggregation, 16-deep MLP unroll ----------------
__device__ inline void agg_row(int beg, int cnt, int lane, const int2* __restrict__ ep,
                               const unsigned short* __restrict__ H, float& a0, float& a1,
                               float& a2, float& a3) {
    int t = 0;
    for (; t + 16 <= cnt; t += 16) {
        int2 e[16];
#pragma unroll
        for (int u = 0; u < 16; u++) e[u] = ep[beg + t + u];
        ushort4 v[16];
#pragma unroll
        for (int u = 0; u < 16; u++)
            v[u] = *(const ushort4*)(H + (size_t)e[u].x * GDIM + lane * 4);
#pragma unroll
        for (int u = 0; u < 16; u++) {
            float w = __int_as_float(e[u].y);
            a0 = fmaf(bf2f(v[u].x), w, a0);
            a1 = fmaf(bf2f(v[u].y), w, a1);
            a2 = fmaf(bf2f(v[u].z), w, a2);
            a3 = fmaf(bf2f(v[u].w), w, a3);
        }
    }
    for (; t + 4 <= cnt; t += 4) {
        int2 e[4];
#pragma unroll
        for (int u = 0; u < 4; u++) e[u] = ep[beg + t + u];
        ushort4 v[4];
#pragma unroll
        for (int u = 0; u < 4; u++)
            v[u] = *(const ushort4*)(H + (size_t)e[u].x * GDIM + lane * 4);
#pragma unroll
        for (int u = 0; u < 4; u++) {
            float w = __int_as_float(e[u].y);
            a0 = fmaf(bf2f(v[u].x), w, a0);
            a1 = fmaf(bf2f(v[u].y), w, a1);
            a2 = fmaf(bf2f(v[u].z), w, a2);
            a3 = fmaf(bf2f(v[u].w), w, a3);
        }
    }
    for (; t < cnt; t++) {
        int2 e = ep[beg + t];
        float w = __int_as_float(e.y);
        ushort4 v = *(const ushort4*)(H + (size_t)e.x * GDIM + lane * 4);
        a0 = fmaf(bf2f(v.x), w, a0);
        a1 = fmaf(bf2f(v.y), w, a1);
        a2 = fmaf(bf2f(v.z), w, a2);
        a3 = fmaf(bf2f(v.w), w, a3);
    }
}

__global__ void aggb_k(const int* __restrict__ row_start, const int* __restrict__ counts,
                       const int2* __restrict__ ep, const unsigned short* __restrict__ H,
                       unsigned short* __restrict__ AGG, int n) {
    int row = blockIdx.x * 4 + (threadIdx.x >> 6);
    int lane = threadIdx.x & 63;
    if (row >= n) return;
    float a0 = 0.f, a1 = 0.f, a2 = 0.f, a3 = 0.f;
    agg_row(row_start[row], counts[row], lane, ep, H, a0, a1, a2, a3);
    *(ushort4*)(AGG + (size_t)row * GDIM + lane * 4) =
        make_ushort4(f2bf(a0), f2bf(a1), f2bf(a2), f2bf(a3));
}

__global__ void aggsel_k(const int* __restrict__ idx, const int* __restrict__ row_start,
                         const int* __restrict__ counts, const int2* __restrict__ ep,
                         const unsigned short* __restrict__ H, unsigned short* __restrict__ AGG) {
    int b = blockIdx.x * 4 + (threadIdx.x >> 6);
    int lane = threadIdx.x & 63;
    int id = idx[b];
    int row = id < 0 ? 0 : id;
    float a0 = 0.f, a1 = 0.f, a2 = 0.f, a3 = 0.f;
    agg_row(row_start[row], counts[row], lane, ep, H, a0, a1, a2, a3);
    *(ushort4*)(AGG + (size_t)b * GDIM + lane * 4) =
        make_ushort4(f2bf(a0), f2bf(a1), f2bf(a2), f2bf(a3));
}

// ---------------- GNN GEMM + fused LN epilogue ----------------
// Tile 128 rows x 256 cols (N=GDIM full width), 512 threads = 8 waves (2x4).
// C = relu(A@B + bias) + R (fp32), LNO = LN(C; ln_s, ln_b) bf16 (next layer's input).
__global__ __launch_bounds__(512) void mgemmln_k(const unsigned short* __restrict__ A,
                                                 const unsigned short* __restrict__ BT,
                                                 const float* __restrict__ bias,
                                                 const float* __restrict__ R,
                                                 const float* __restrict__ ln_s,
                                                 const float* __restrict__ ln_b,
                                                 float* __restrict__ C,
                                                 unsigned short* __restrict__ LNO, int M) {
    __shared__ unsigned short As[128 * 32];
    __shared__ unsigned short Bs[256 * 32];
    __shared__ float rsum[128], rsq[128];
    int m0 = blockIdx.x * 128;
    int tid = threadIdx.x;
    int wave = tid >> 6, lane = tid & 63;
    int wr = wave >> 2, wc = wave & 3;
    int wm = wr * 64, wn = wc * 64;
    int lrow = lane & 15, lq = lane >> 4;

    f32x4 acc[4][4];
    const f32x4 zz = {0.f, 0.f, 0.f, 0.f};
#pragma unroll
    for (int i = 0; i < 4; i++)
#pragma unroll
        for (int j = 0; j < 4; j++) acc[i][j] = zz;

    int r0 = tid >> 2;   // 0..127
    int q = tid & 3;

    for (int k0 = 0; k0 < GDIM; k0 += 32) {
        {
            int gm = m0 + r0;
            uint4 va = make_uint4(0, 0, 0, 0);
            if (gm < M) va = *(const uint4*)(A + (size_t)gm * GDIM + k0 + q * 8);
            *(uint4*)&As[r0 * 32 + q * 8] = va;
        }
#pragma unroll
        for (int p = 0; p < 2; p++) {
            int rr = r0 + p * 128;
            *(uint4*)&Bs[rr * 32 + q * 8] = *(const uint4*)(BT + (size_t)rr * GDIM + k0 + q * 8);
        }
        __syncthreads();
        bf16x8 af[4], bfr[4];
#pragma unroll
        for (int i = 0; i < 4; i++)
            af[i] = *(const bf16x8*)&As[(wm + i * 16 + lrow) * 32 + lq * 8];
#pragma unroll
        for (int j = 0; j < 4; j++)
            bfr[j] = *(const bf16x8*)&Bs[(wn + j * 16 + lrow) * 32 + lq * 8];
#pragma unroll
        for (int i = 0; i < 4; i++)
#pragma unroll
            for (int j = 0; j < 4; j++)
                acc[i][j] =
                    __builtin_amdgcn_mfma_f32_16x16x32_bf16(af[i], bfr[j], acc[i][j], 0, 0, 0);
        __syncthreads();
    }

    // zero LN accumulators
    for (int z = tid; z < 128; z += 512) {
        rsum[z] = 0.f;
        rsq[z] = 0.f;
    }
    __syncthreads();

    // epilogue: v = relu(acc+bias) + R; write C; keep v in acc
#pragma unroll
    for (int i = 0; i < 4; i++) {
#pragma unroll
        for (int j = 0; j < 4; j++) {
            int gn = wn + j * 16 + lrow;
            float bv = bias[gn];
#pragma unroll
            for (int r = 0; r < 4; r++) {
                int gml = wm + i * 16 + lq * 4 + r;
                int gm = m0 + gml;
                float v = fmaxf(acc[i][j][r] + bv, 0.f);
                if (gm < M) {
                    v += R[(size_t)gm * GDIM + gn];
                    C[(size_t)gm * GDIM + gn] = v;
                }
                acc[i][j][r] = v;
            }
        }
    }
    // row partial sums (each wave covers 64 cols of its 64 rows)
#pragma unroll
    for (int i = 0; i < 4; i++) {
#pragma unroll
        for (int r = 0; r < 4; r++) {
            float s1 = 0.f, s2 = 0.f;
#pragma unroll
            for (int j = 0; j < 4; j++) {
                float v = acc[i][j][r];
                s1 += v;
                s2 += v * v;
            }
#pragma unroll
            for (int m = 1; m <= 8; m <<= 1) {
                s1 += __shfl_xor(s1, m);
                s2 += __shfl_xor(s2, m);
            }
            if (lrow == 0) {
                int rl = wm + i * 16 + lq * 4 + r;
                atomicAdd(&rsum[rl], s1);
                atomicAdd(&rsq[rl], s2);
            }
        }
    }
    __syncthreads();
    // normalize -> bf16
#pragma unroll
    for (int i = 0; i < 4; i++) {
#pragma unroll
        for (int j = 0; j < 4; j++) {
            int gn = wn + j * 16 + lrow;
            float sc = ln_s[gn], bi = ln_b[gn];
#pragma unroll
            for (int r = 0; r < 4; r++) {
                int rl = wm + i * 16 + lq * 4 + r;
                int gm = m0 + rl;
                if (gm >= M) continue;
                float mu = rsum[rl] * (1.f / GDIM);
                float var = rsq[rl] * (1.f / GDIM) - mu * mu;
                float rstd = rsqrtf(var + 1e-5f);
                float o = (acc[i][j][r] - mu) * rstd * sc + bi;
                LNO[(size_t)gm * GDIM + gn] = f2bf(o);
            }
        }
    }
}

// ---------------- bf16 MFMA full-K, bf16 out, fused epilogue (small GEMMs) ----------------
// 64x64 tile, 4 waves stacked in M. ACT: 0 none, 1 relu, 2 gelu.
// EPI: 0 plain, 1 OOV-replace (aux=oov_emb), 2 indexed-residual (aux=R [NNODES x N]).
template <int ACT, int EPI>
__global__ __launch_bounds__(256) void mfull_k(const unsigned short* __restrict__ A,
                                               const unsigned short* __restrict__ BT,
                                               const float* __restrict__ bias,
                                               const int* __restrict__ idx,
                                               const float* __restrict__ aux,
                                               unsigned short* __restrict__ O, int M, int N,
                                               int K) {
    __shared__ unsigned short As[64 * 32];
    __shared__ unsigned short Bs[64 * 32];
    int m0 = blockIdx.y * 64, n0 = blockIdx.x * 64;
    int tid = threadIdx.x;
    int wave = tid >> 6, lane = tid & 63;
    int wm = wave * 16;
    int lrow = lane & 15, lq = lane >> 4;
    f32x4 acc[4];
    const f32x4 zz = {0.f, 0.f, 0.f, 0.f};
#pragma unroll
    for (int j = 0; j < 4; j++) acc[j] = zz;
    int r0 = tid >> 2;
    int q = tid & 3;
    for (int k0 = 0; k0 < K; k0 += 32) {
        *(uint4*)&As[r0 * 32 + q * 8] = *(const uint4*)(A + (size_t)(m0 + r0) * K + k0 + q * 8);
        *(uint4*)&Bs[r0 * 32 + q * 8] = *(const uint4*)(BT + (size_t)(n0 + r0) * K + k0 + q * 8);
        __syncthreads();
        bf16x8 af = *(const bf16x8*)&As[(wm + lrow) * 32 + lq * 8];
#pragma unroll
        for (int j = 0; j < 4; j++) {
            bf16x8 bfr = *(const bf16x8*)&Bs[(j * 16 + lrow) * 32 + lq * 8];
            acc[j] = __builtin_amdgcn_mfma_f32_16x16x32_bf16(af, bfr, acc[j], 0, 0, 0);
        }
        __syncthreads();
    }
#pragma unroll
    for (int j = 0; j < 4; j++) {
        int gn = n0 + j * 16 + lrow;
        float bv = bias[gn];
#pragma unroll
        for (int r = 0; r < 4; r++) {
            int gm = m0 + wm + lq * 4 + r;
            float v = acc[j][r] + bv;
            if (ACT == 1) v = fmaxf(v, 0.f);
            if (ACT == 2) v = 0.5f * v * (1.f + erff(v * 0.70710678118654752f));
            if (EPI == 2) {
                int id = idx[gm];
                int safe = id < 0 ? 0 : id;
                v += aux[(size_t)safe * N + gn];
            }
            if (EPI == 1) {
                if (idx[gm] < 0) v = aux[gn];
            }
            O[(size_t)gm * N + gn] = f2bf(v);
        }
    }
}

// ---------------- fused split-K GEMM + last-block reduce/LN (head, M=256, N=512) ----------------
// grid (8, 4, S). Partials in part[s][256][512]; counter per m-tile; last arriving block
// reduces its 64 rows: + bias (+hbuf residual) -> hbuf fp32; LN -> bf16 (or plain bf16).
template <int S, bool RESID, bool DO_LN>
__global__ __launch_bounds__(256) void mskf_k(const unsigned short* __restrict__ A,
                                              const unsigned short* __restrict__ BT,
                                              const float* __restrict__ bias,
                                              const float* __restrict__ ln_s,
                                              const float* __restrict__ ln_b,
                                              float* __restrict__ hbuf,
                                              unsigned short* __restrict__ outbf,
                                              float* __restrict__ part, int* __restrict__ ctr,
                                              int K) {
    __shared__ unsigned short As[64 * 32];
    __shared__ unsigned short Bs[64 * 32];
    __shared__ int lastf;
    int m0 = blockIdx.y * 64, n0 = blockIdx.x * 64;
    int kchunk = K / S;
    int kbeg = blockIdx.z * kchunk;
    float* C = part + (size_t)blockIdx.z * BSZ * HID;
    int tid = threadIdx.x;
    int wave = tid >> 6, lane = tid & 63;
    int wm = wave * 16;
    int lrow = lane & 15, lq = lane >> 4;
    f32x4 acc[4];
    const f32x4 zz = {0.f, 0.f, 0.f, 0.f};
#pragma unroll
    for (int j = 0; j < 4; j++) acc[j] = zz;
    int r0 = tid >> 2;
    int q = tid & 3;
    for (int k0 = kbeg; k0 < kbeg + kchunk; k0 += 32) {
        *(uint4*)&As[r0 * 32 + q * 8] = *(const uint4*)(A + (size_t)(m0 + r0) * K + k0 + q * 8);
        *(uint4*)&Bs[r0 * 32 + q * 8] = *(const uint4*)(BT + (size_t)(n0 + r0) * K + k0 + q * 8);
        __syncthreads();
        bf16x8 af = *(const bf16x8*)&As[(wm + lrow) * 32 + lq * 8];
#pragma unroll
        for (int j = 0; j < 4; j++) {
            bf16x8 bfr = *(const bf16x8*)&Bs[(j * 16 + lrow) * 32 + lq * 8];
            acc[j] = __builtin_amdgcn_mfma_f32_16x16x32_bf16(af, bfr, acc[j], 0, 0, 0);
        }
        __syncthreads();
    }
#pragma unroll
    for (int j = 0; j < 4; j++) {
        int gn = n0 + j * 16 + lrow;
#pragma unroll
        for (int r = 0; r < 4; r++) {
            int gm = m0 + wm + lq * 4 + r;
            C[(size_t)gm * HID + gn] = acc[j][r];
        }
    }
    __threadfence();
    if (tid == 0) {
        int done = atomicAdd(&ctr[blockIdx.y], 1);
        lastf = (done == 8 * S - 1) ? 1 : 0;
    }
    __syncthreads();
    if (!lastf) return;
    __threadfence();

    // epilogue: rows [m0_y*64, +64), full N=512
    const float4* bb = (const float4*)bias;
    float4 cb0 = bb[lane * 2], cb1 = bb[lane * 2 + 1];
    for (int it = 0; it < 16; it++) {
        int row = blockIdx.y * 64 + wave * 16 + it;
        float4 a0 = {0.f, 0.f, 0.f, 0.f}, a1 = a0;
        for (int s = 0; s < S; s++) {
            const float4* pp = (const float4*)(part + ((size_t)s * BSZ + row) * HID);
            float4 b0 = pp[lane * 2], b1 = pp[lane * 2 + 1];
            a0.x += b0.x; a0.y += b0.y; a0.z += b0.z; a0.w += b0.w;
            a1.x += b1.x; a1.y += b1.y; a1.z += b1.z; a1.w += b1.w;
        }
        a0.x += cb0.x; a0.y += cb0.y; a0.z += cb0.z; a0.w += cb0.w;
        a1.x += cb1.x; a1.y += cb1.y; a1.z += cb1.z; a1.w += cb1.w;
        float4* hp = (float4*)(hbuf + (size_t)row * HID);
        if (RESID) {
            float4 r0v = hp[lane * 2], r1v = hp[lane * 2 + 1];
            a0.x += r0v.x; a0.y += r0v.y; a0.z += r0v.z; a0.w += r0v.w;
            a1.x += r1v.x; a1.y += r1v.y; a1.z += r1v.z; a1.w += r1v.w;
        }
        hp[lane * 2] = a0;
        hp[lane * 2 + 1] = a1;
        unsigned short* op = outbf + (size_t)row * HID;
        if (DO_LN) {
            float sum = a0.x + a0.y + a0.z + a0.w + a1.x + a1.y + a1.z + a1.w;
#pragma unroll
            for (int off = 32; off >= 1; off >>= 1) sum += __shfl_xor(sum, off);
            float mu = sum / HID;
            float d0 = a0.x - mu, d1 = a0.y - mu, d2 = a0.z - mu, d3 = a0.w - mu;
            float d4 = a1.x - mu, d5 = a1.y - mu, d6 = a1.z - mu, d7 = a1.w - mu;
            float sq =
                d0 * d0 + d1 * d1 + d2 * d2 + d3 * d3 + d4 * d4 + d5 * d5 + d6 * d6 + d7 * d7;
#pragma unroll
            for (int off = 32; off >= 1; off >>= 1) sq += __shfl_xor(sq, off);
            float rstd = rsqrtf(sq / HID + 1e-5f);
            const float4* sp = (const float4*)ln_s;
            const float4* bp = (const float4*)ln_b;
            float4 s0 = sp[lane * 2], s1 = sp[lane * 2 + 1];
            float4 t0 = bp[lane * 2], t1 = bp[lane * 2 + 1];
            *(ushort4*)(op + lane * 8) =
                make_ushort4(f2bf(d0 * rstd * s0.x + t0.x), f2bf(d1 * rstd * s0.y + t0.y),
                             f2bf(d2 * rstd * s0.z + t0.z), f2bf(d3 * rstd * s0.w + t0.w));
            *(ushort4*)(op + lane * 8 + 4) =
                make_ushort4(f2bf(d4 * rstd * s1.x + t1.x), f2bf(d5 * rstd * s1.y + t1.y),
                             f2bf(d6 * rstd * s1.z + t1.z), f2bf(d7 * rstd * s1.w + t1.w));
        } else {
            *(ushort4*)(op + lane * 8) =
                make_ushort4(f2bf(a0.x), f2bf(a0.y), f2bf(a0.z), f2bf(a0.w));
            *(ushort4*)(op + lane * 8 + 4) =
                make_ushort4(f2bf(a1.x), f2bf(a1.y), f2bf(a1.z), f2bf(a1.w));
        }
    }
}

// ---------------- bf16 MFMA GEMM 128x128 (logits) ----------------
template <int ACT, bool RES, bool BIAS>
__global__ __launch_bounds__(256) void mgemm_k(const unsigned short* __restrict__ A,
                                               const unsigned short* __restrict__ BT,
                                               const float* __restrict__ bias,
                                               const float* __restrict__ R,
                                               float* __restrict__ C, int M, int N, int K) {
    __shared__ unsigned short As[128 * 32];
    __shared__ unsigned short Bs[128 * 32];
    int m0 = blockIdx.y * 128, n0 = blockIdx.x * 128;
    int tid = threadIdx.x;
    int wave = tid >> 6, lane = tid & 63;
    int wm = (wave >> 1) * 64, wn = (wave & 1) * 64;
    int lrow = lane & 15, lq = lane >> 4;

    f32x4 acc[4][4];
    const f32x4 zz = {0.f, 0.f, 0.f, 0.f};
#pragma unroll
    for (int i = 0; i < 4; i++)
#pragma unroll
        for (int j = 0; j < 4; j++) acc[i][j] = zz;

    int r0 = tid >> 2;
    int q = tid & 3;

    for (int k0 = 0; k0 < K; k0 += 32) {
#pragma unroll
        for (int p = 0; p < 2; p++) {
            int row = r0 + p * 64;
            int gm = m0 + row;
            uint4 va = make_uint4(0, 0, 0, 0);
            if (gm < M) va = *(const uint4*)(A + (size_t)gm * K + k0 + q * 8);
            *(uint4*)&As[row * 32 + q * 8] = va;
            int gn = n0 + row;
            uint4 vb = make_uint4(0, 0, 0, 0);
            if (gn < N) vb = *(const uint4*)(BT + (size_t)gn * K + k0 + q * 8);
            *(uint4*)&Bs[row * 32 + q * 8] = vb;
        }
        __syncthreads();
        bf16x8 af[4], bfr[4];
#pragma unroll
        for (int i = 0; i < 4; i++)
            af[i] = *(const bf16x8*)&As[(wm + i * 16 + lrow) * 32 + lq * 8];
#pragma unroll
        for (int j = 0; j < 4; j++)
            bfr[j] = *(const bf16x8*)&Bs[(wn + j * 16 + lrow) * 32 + lq * 8];
#pragma unroll
        for (int i = 0; i < 4; i++)
#pragma unroll
            for (int j = 0; j < 4; j++)
                acc[i][j] =
                    __builtin_amdgcn_mfma_f32_16x16x32_bf16(af[i], bfr[j], acc[i][j], 0, 0, 0);
        __syncthreads();
    }

#pragma unroll
    for (int i = 0; i < 4; i++) {
#pragma unroll
        for (int j = 0; j < 4; j++) {
            int gn = n0 + wn + j * 16 + lrow;
            if (gn >= N) continue;
            float bv = BIAS ? bias[gn] : 0.f;
#pragma unroll
            for (int r = 0; r < 4; r++) {
                int gm = m0 + wm + i * 16 + lq * 4 + r;
                if (gm >= M) continue;
                float v = acc[i][j][r] + bv;
                if (ACT == 1) v = fmaxf(v, 0.f);
                if (RES) v += R[(size_t)gm * N + gn];
                C[(size_t)gm * N + gn] = v;
            }
        }
    }
}

// ---------------- launch ----------------
extern "C" void kernel_launch(void* const* d_in, const int* in_sizes, int n_in,
                              void* d_out, int out_size, void* d_ws, size_t ws_size,
                              hipStream_t stream) {
    const int* node_indices = (const int*)d_in[0];
    const int* edge_src = (const int*)d_in[1];
    const int* edge_dst = edge_src + NEDGES;
    const float* edge_w = (const float*)d_in[2];
    const float* partial_emb = (const float*)d_in[3];
    const float* oov_emb = (const float*)d_in[4];
    const float* gnn_ln_s = (const float*)d_in[5];
    const float* gnn_ln_b = (const float*)d_in[6];
    const float* gnn_w = (const float*)d_in[7];
    const float* gnn_b = (const float*)d_in[8];
    const float* post_w = (const float*)d_in[9];
    const float* post_b = (const float*)d_in[10];
    const float* pin_w = (const float*)d_in[11];
    const float* pin_b = (const float*)d_in[12];
    const float* blk_ln_s = (const float*)d_in[13];
    const float* blk_ln_b = (const float*)d_in[14];
    const float* blk_w1 = (const float*)d_in[15];
    const float* blk_b1 = (const float*)d_in[16];
    const float* blk_w2 = (const float*)d_in[17];
    const float* blk_b2 = (const float*)d_in[18];
    const float* pout_w = (const float*)d_in[19];
    const float* pout_b = (const float*)d_in[20];
    const float* gene = (const float*)d_in[21];
    float* out = (float*)d_out;

    char* p = (char*)d_ws;
    auto alloc = [&](size_t bytes) {
        char* r = p;
        p += (bytes + 255) & ~(size_t)255;
        return r;
    };
    int* counts = (int*)alloc(NNODES * 4 + 256);   // counts + 64 fused-split-K counters
    int* ctr = counts + NNODES;
    int* row_start = (int*)alloc(NNODES * 4);
    int* cursor = (int*)alloc(NNODES * 4);
    int2* epack = (int2*)alloc((size_t)NEDGES * 8);
    // 'part': GNN phase = ln_bf + aggbf (bf16); head phase = split-K fp32 partials
    float* part = (float*)alloc((size_t)NNODES * GDIM * 4);
    unsigned short* ln_bf = (unsigned short*)part;
    unsigned short* aggbf = (unsigned short*)((char*)part + (size_t)NNODES * GDIM * 2);
    float* xa = (float*)alloc((size_t)NNODES * GDIM * 4);
    float* xb = (float*)alloc((size_t)NNODES * GDIM * 4);
    float* hbuf = (float*)alloc((size_t)BSZ * HID * 4);
    unsigned short* aggselb = (unsigned short*)alloc((size_t)BSZ * GDIM * 2);
    unsigned short* pertinbf = (unsigned short*)alloc((size_t)BSZ * GDIM * 2);
    unsigned short* pertbf = (unsigned short*)alloc((size_t)BSZ * GDIM * 2);
    unsigned short* zlnbf = (unsigned short*)alloc((size_t)BSZ * HID * 2);
    unsigned short* z1bf = (unsigned short*)alloc((size_t)BSZ * INNER * 2);
    unsigned short* hbufbf = (unsigned short*)alloc((size_t)BSZ * HID * 2);
    unsigned short* projb = (unsigned short*)alloc((size_t)BSZ * NCLS * RANK * 2);
    unsigned short* gnnT = (unsigned short*)alloc((size_t)3 * GDIM * GDIM * 2);
    unsigned short* postT = (unsigned short*)alloc((size_t)GDIM * GDIM * 2);
    unsigned short* pinT = (unsigned short*)alloc((size_t)HID * GDIM * 2);
    unsigned short* w1T = (unsigned short*)alloc((size_t)6 * INNER * HID * 2);
    unsigned short* w2T = (unsigned short*)alloc((size_t)6 * HID * INNER * 2);
    unsigned short* poutT = (unsigned short*)alloc((size_t)NCLS * RANK * HID * 2);
    unsigned short* geneb = (unsigned short*)alloc((size_t)NGENES * RANK * 2);

    const int EB = (NEDGES + 255) / 256;

    // zero counts + split-K counters; convert all weights in one dispatch
    hipMemsetAsync(counts, 0, NNODES * 4 + 256, stream);
    convall_k<<<15100, dim3(32, 8), 0, stream>>>(gnn_w, post_w, pin_w, blk_w1, blk_w2, pout_w,
                                                 gene, gnnT, postT, pinT, w1T, w2T, poutT, geneb);

    // CSR build: hist -> single-block scan -> scatter
    hist_k<<<EB, 256, 0, stream>>>(edge_dst, counts, NEDGES);
    scanall_k<<<1, 1024, 0, stream>>>(counts, row_start, cursor, NNODES);
    scatter_k<<<EB, 256, 0, stream>>>(edge_src, edge_dst, edge_w, cursor, epack, NEDGES);

    // GNN: L1 (lnb from partial_emb), L1/L2 GEMM+LN fused, L3 selective
    lnb_k<<<(NNODES + 3) / 4, 256, 0, stream>>>(partial_emb, gnn_ln_s, gnn_ln_b, ln_bf, NNODES);
    aggb_k<<<(NNODES + 3) / 4, 256, 0, stream>>>(row_start, counts, epack, ln_bf, aggbf, NNODES);
    mgemmln_k<<<(NNODES + 127) / 128, 512, 0, stream>>>(
        aggbf, gnnT, gnn_b, partial_emb, gnn_ln_s + GDIM, gnn_ln_b + GDIM, xa, ln_bf, NNODES);
    aggb_k<<<(NNODES + 3) / 4, 256, 0, stream>>>(row_start, counts, epack, ln_bf, aggbf, NNODES);
    mgemmln_k<<<(NNODES + 127) / 128, 512, 0, stream>>>(
        aggbf, gnnT + (size_t)GDIM * GDIM, gnn_b + GDIM, xa, gnn_ln_s + 2 * GDIM,
        gnn_ln_b + 2 * GDIM, xb, ln_bf, NNODES);
    aggsel_k<<<BSZ / 4, 256, 0, stream>>>(node_indices, row_start, counts, epack, ln_bf, aggselb);
    mfull_k<1, 2><<<dim3(GDIM / 64, BSZ / 64), 256, 0, stream>>>(
        aggselb, gnnT + (size_t)2 * GDIM * GDIM, gnn_b + 2 * GDIM, node_indices, xb, pertinbf,
        BSZ, GDIM, GDIM);

    // post_mp + OOV replace
    mfull_k<0, 1><<<dim3(GDIM / 64, BSZ / 64), 256, 0, stream>>>(
        pertinbf, postT, post_b, node_indices, oov_emb, pertbf, BSZ, GDIM, GDIM);

    // pin (full-K, fused reduce+LN via counter slot 0)
    mskf_k<1, false, true><<<dim3(8, 4, 1), 256, 0, stream>>>(
        pertbf, pinT, pin_b, blk_ln_s, blk_ln_b, hbuf, zlnbf, part, ctr, GDIM);

    // 6 head blocks
    for (int i = 0; i < 6; i++) {
        mfull_k<2, 0><<<dim3(INNER / 64, BSZ / 64), 256, 0, stream>>>(
            zlnbf, w1T + (size_t)i * INNER * HID, blk_b1 + i * INNER, nullptr, nullptr, z1bf, BSZ,
            INNER, HID);
        if (i < 5) {
            mskf_k<4, true, true><<<dim3(8, 4, 4), 256, 0, stream>>>(
                z1bf, w2T + (size_t)i * HID * INNER, blk_b2 + i * HID,
                blk_ln_s + (i + 1) * HID, blk_ln_b + (i + 1) * HID, hbuf, zlnbf, part,
                ctr + 4 * (1 + i), INNER);
        } else {
            mskf_k<4, true, false><<<dim3(8, 4, 4), 256, 0, stream>>>(
                z1bf, w2T + (size_t)i * HID * INNER, blk_b2 + i * HID, nullptr, nullptr, hbuf,
                hbufbf, part, ctr + 4 * (1 + i), INNER);
        }
    }

    // pout (fully fused)
    mfull_k<0, 0><<<dim3((NCLS * RANK) / 64, BSZ / 64), 256, 0, stream>>>(
        hbufbf, poutT, pout_b, nullptr, nullptr, projb, BSZ, NCLS * RANK, HID);

    // logits
    mgemm_k<0, false, false><<<dim3((NGENES + 127) / 128, (BSZ * NCLS) / 128), 256, 0, stream>>>(
        projb, geneb, nullptr, nullptr, out, BSZ * NCLS, NGENES, RANK);
}

// Round 7
// 631.848 us; speedup vs baseline: 1.4107x; 1.4107x over previous
//
#include <hip/hip_runtime.h>
#include <hip/hip_bf16.h>
#include <math.h>

#define NNODES 20000
#define NEDGES 640000
#define BSZ 256
#define GDIM 256
#define HID 512
#define INNER 2048
#define RANK 512
#define NCLS 3
#define NGENES 6640

typedef __attribute__((ext_vector_type(8))) short bf16x8;
typedef __attribute__((ext_vector_type(4))) float f32x4;

__device__ inline float bf2f(unsigned short u) {
    return __uint_as_float(((unsigned)u) << 16);
}
__device__ inline unsigned short f2bf(float f) {
    unsigned u = __float_as_uint(f);
    u = u + 0x7fff + ((u >> 16) & 1);   // RNE
    return (unsigned short)(u >> 16);
}

// ---------------- CSR build ----------------
__global__ void hist_k(const int* __restrict__ dst, int* __restrict__ counts, int E) {
    int e = blockIdx.x * 256 + threadIdx.x;
    if (e < E) atomicAdd(&counts[dst[e]], 1);
}

// single-block scan over counts -> row_start/cursor (n <= 20480)
__global__ __launch_bounds__(1024) void scanall_k(const int* __restrict__ counts,
                                                  int* __restrict__ row_start,
                                                  int* __restrict__ cursor, int n) {
    __shared__ int tsum[1024];
    int t = threadIdx.x;
    int base = t * 20;
    int s = 0;
#pragma unroll 4
    for (int i = 0; i < 20; i++) {
        int idx = base + i;
        s += (idx < n) ? counts[idx] : 0;
    }
    tsum[t] = s;
    __syncthreads();
    for (int off = 1; off < 1024; off <<= 1) {
        int v = (t >= off) ? tsum[t - off] : 0;
        __syncthreads();
        tsum[t] += v;
        __syncthreads();
    }
    int run = (t == 0) ? 0 : tsum[t - 1];
    for (int i = 0; i < 20; i++) {
        int idx = base + i;
        if (idx < n) {
            row_start[idx] = run;
            cursor[idx] = run;
            run += counts[idx];
        }
    }
}

__global__ void scatter_k(const int* __restrict__ src, const int* __restrict__ dst,
                          const float* __restrict__ w, int* __restrict__ cursor,
                          int2* __restrict__ ep, int E) {
    int e = blockIdx.x * 256 + threadIdx.x;
    if (e < E) {
        int d = dst[e];
        int p = atomicAdd(&cursor[d], 1);
        ep[p] = make_int2(src[e], __float_as_int(w[e]));
    }
}

// ---------------- mega conversion kernel: all weight transposes + gene cast ----------------
__global__ void convall_k(const float* __restrict__ gnn_w, const float* __restrict__ post_w,
                          const float* __restrict__ pin_w, const float* __restrict__ blk_w1,
                          const float* __restrict__ blk_w2, const float* __restrict__ pout_w,
                          const float* __restrict__ gene, unsigned short* __restrict__ gnnT,
                          unsigned short* __restrict__ postT, unsigned short* __restrict__ pinT,
                          unsigned short* __restrict__ w1T, unsigned short* __restrict__ w2T,
                          unsigned short* __restrict__ poutT,
                          unsigned short* __restrict__ geneb) {
    __shared__ float s[32][33];
    int bid = blockIdx.x;
    int tx = threadIdx.x, ty = threadIdx.y;
    const float* W;
    unsigned short* WT;
    int K, N, k0, n0;
    if (bid < 192) {
        int l = bid >> 6, rem = bid & 63;
        W = gnn_w + (size_t)l * GDIM * GDIM;
        WT = gnnT + (size_t)l * GDIM * GDIM;
        K = GDIM; N = GDIM;
        n0 = (rem & 7) * 32; k0 = (rem >> 3) * 32;
    } else if (bid < 256) {
        int rem = bid - 192;
        W = post_w; WT = postT; K = GDIM; N = GDIM;
        n0 = (rem & 7) * 32; k0 = (rem >> 3) * 32;
    } else if (bid < 384) {
        int rem = bid - 256;
        W = pin_w; WT = pinT; K = GDIM; N = HID;
        n0 = (rem & 15) * 32; k0 = (rem >> 4) * 32;
    } else if (bid < 6528) {
        int rem = bid - 384;
        int l = rem >> 10; rem &= 1023;
        W = blk_w1 + (size_t)l * HID * INNER;
        WT = w1T + (size_t)l * HID * INNER;
        K = HID; N = INNER;
        n0 = (rem & 63) * 32; k0 = (rem >> 6) * 32;
    } else if (bid < 12672) {
        int rem = bid - 6528;
        int l = rem >> 10; rem &= 1023;
        W = blk_w2 + (size_t)l * INNER * HID;
        WT = w2T + (size_t)l * INNER * HID;
        K = INNER; N = HID;
        n0 = (rem & 15) * 32; k0 = (rem >> 4) * 32;
    } else if (bid < 13440) {
        int rem = bid - 12672;
        W = pout_w; WT = poutT; K = HID; N = NCLS * RANK;
        n0 = (rem % 48) * 32; k0 = (rem / 48) * 32;
    } else {
        int i8 = (bid - 13440) * 256 + ty * 32 + tx;
        const float4* xp = (const float4*)gene;
        float4 a = xp[i8 * 2], b = xp[i8 * 2 + 1];
        *(ushort4*)(geneb + (size_t)i8 * 8) =
            make_ushort4(f2bf(a.x), f2bf(a.y), f2bf(a.z), f2bf(a.w));
        *(ushort4*)(geneb + (size_t)i8 * 8 + 4) =
            make_ushort4(f2bf(b.x), f2bf(b.y), f2bf(b.z), f2bf(b.w));
        return;
    }
#pragma unroll
    for (int i = 0; i < 4; i++)
        s[ty + 8 * i][tx] = W[(size_t)(k0 + ty + 8 * i) * N + n0 + tx];
    __syncthreads();
#pragma unroll
    for (int i = 0; i < 4; i++)
        WT[(size_t)(n0 + ty + 8 * i) * K + k0 + tx] = f2bf(s[tx][ty + 8 * i]);
}

// ---------------- GNN LayerNorm (D=256), bf16 out (layer-1 input only) ----------------
__global__ void lnb_k(const float* __restrict__ X, const float* __restrict__ sc,
                      const float* __restrict__ bi, unsigned short* __restrict__ Y, int M) {
    int row = blockIdx.x * 4 + (threadIdx.x >> 6);
    int lane = threadIdx.x & 63;
    if (row >= M) return;
    float4 v = ((const float4*)(X + (size_t)row * GDIM))[lane];
    float sum = v.x + v.y + v.z + v.w;
#pragma unroll
    for (int off = 32; off >= 1; off >>= 1) sum += __shfl_xor(sum, off);
    float mu = sum / GDIM;
    float a = v.x - mu, b = v.y - mu, c = v.z - mu, d = v.w - mu;
    float sq = a * a + b * b + c * c + d * d;
#pragma unroll
    for (int off = 32; off >= 1; off >>= 1) sq += __shfl_xor(sq, off);
    float rstd = rsqrtf(sq / GDIM + 1e-5f);
    float4 s4 = ((const float4*)sc)[lane];
    float4 b4 = ((const float4*)bi)[lane];
    *(ushort4*)(Y + (size_t)row * GDIM + lane * 4) =
        make_ushort4(f2bf(a * rstd * s4.x + b4.x), f2bf(b * rstd * s4.y + b4.y),
                     f2bf(c * rstd * s4.z + b4.z), f2bf(d * rstd * s4.w + b4.w));
}

// ---------------- CSR aggregation, 16-deep MLP unroll ----------------
__device__ inline void agg_row(int beg, int cnt, int lane, const int2* __restrict__ ep,
                               const unsigned short* __restrict__ H, float& a0, float& a1,
                               float& a2, float& a3) {
    int t = 0;
    for (; t + 16 <= cnt; t += 16) {
        int2 e[16];
#pragma unroll
        for (int u = 0; u < 16; u++) e[u] = ep[beg + t + u];
        ushort4 v[16];
#pragma unroll
        for (int u = 0; u < 16; u++)
            v[u] = *(const ushort4*)(H + (size_t)e[u].x * GDIM + lane * 4);
#pragma unroll
        for (int u = 0; u < 16; u++) {
            float w = __int_as_float(e[u].y);
            a0 = fmaf(bf2f(v[u].x), w, a0);
            a1 = fmaf(bf2f(v[u].y), w, a1);
            a2 = fmaf(bf2f(v[u].z), w, a2);
            a3 = fmaf(bf2f(v[u].w), w, a3);
        }
    }
    for (; t + 4 <= cnt; t += 4) {
        int2 e[4];
#pragma unroll
        for (int u = 0; u < 4; u++) e[u] = ep[beg + t + u];
        ushort4 v[4];
#pragma unroll
        for (int u = 0; u < 4; u++)
            v[u] = *(const ushort4*)(H + (size_t)e[u].x * GDIM + lane * 4);
#pragma unroll
        for (int u = 0; u < 4; u++) {
            float w = __int_as_float(e[u].y);
            a0 = fmaf(bf2f(v[u].x), w, a0);
            a1 = fmaf(bf2f(v[u].y), w, a1);
            a2 = fmaf(bf2f(v[u].z), w, a2);
            a3 = fmaf(bf2f(v[u].w), w, a3);
        }
    }
    for (; t < cnt; t++) {
        int2 e = ep[beg + t];
        float w = __int_as_float(e.y);
        ushort4 v = *(const ushort4*)(H + (size_t)e.x * GDIM + lane * 4);
        a0 = fmaf(bf2f(v.x), w, a0);
        a1 = fmaf(bf2f(v.y), w, a1);
        a2 = fmaf(bf2f(v.z), w, a2);
        a3 = fmaf(bf2f(v.w), w, a3);
    }
}

__global__ void aggb_k(const int* __restrict__ row_start, const int* __restrict__ counts,
                       const int2* __restrict__ ep, const unsigned short* __restrict__ H,
                       unsigned short* __restrict__ AGG, int n) {
    int row = blockIdx.x * 4 + (threadIdx.x >> 6);
    int lane = threadIdx.x & 63;
    if (row >= n) return;
    float a0 = 0.f, a1 = 0.f, a2 = 0.f, a3 = 0.f;
    agg_row(row_start[row], counts[row], lane, ep, H, a0, a1, a2, a3);
    *(ushort4*)(AGG + (size_t)row * GDIM + lane * 4) =
        make_ushort4(f2bf(a0), f2bf(a1), f2bf(a2), f2bf(a3));
}

__global__ void aggsel_k(const int* __restrict__ idx, const int* __restrict__ row_start,
                         const int* __restrict__ counts, const int2* __restrict__ ep,
                         const unsigned short* __restrict__ H, unsigned short* __restrict__ AGG) {
    int b = blockIdx.x * 4 + (threadIdx.x >> 6);
    int lane = threadIdx.x & 63;
    int id = idx[b];
    int row = id < 0 ? 0 : id;
    float a0 = 0.f, a1 = 0.f, a2 = 0.f, a3 = 0.f;
    agg_row(row_start[row], counts[row], lane, ep, H, a0, a1, a2, a3);
    *(ushort4*)(AGG + (size_t)b * GDIM + lane * 4) =
        make_ushort4(f2bf(a0), f2bf(a1), f2bf(a2), f2bf(a3));
}

// ---------------- GNN GEMM + fused LN epilogue ----------------
// Tile 128 rows x 256 cols (N=GDIM full width), 512 threads = 8 waves (2x4).
// C = relu(A@B + bias) + R (fp32), LNO = LN(C) bf16.
__global__ __launch_bounds__(512) void mgemmln_k(const unsigned short* __restrict__ A,
                                                 const unsigned short* __restrict__ BT,
                                                 const float* __restrict__ bias,
                                                 const float* __restrict__ R,
                                                 const float* __restrict__ ln_s,
                                                 const float* __restrict__ ln_b,
                                                 float* __restrict__ C,
                                                 unsigned short* __restrict__ LNO, int M) {
    __shared__ unsigned short As[128 * 32];
    __shared__ unsigned short Bs[256 * 32];
    __shared__ float rsum[128], rsq[128];
    int m0 = blockIdx.x * 128;
    int tid = threadIdx.x;
    int wave = tid >> 6, lane = tid & 63;
    int wr = wave >> 2, wc = wave & 3;
    int wm = wr * 64, wn = wc * 64;
    int lrow = lane & 15, lq = lane >> 4;

    f32x4 acc[4][4];
    const f32x4 zz = {0.f, 0.f, 0.f, 0.f};
#pragma unroll
    for (int i = 0; i < 4; i++)
#pragma unroll
        for (int j = 0; j < 4; j++) acc[i][j] = zz;

    int r0 = tid >> 2;
    int q = tid & 3;

    for (int k0 = 0; k0 < GDIM; k0 += 32) {
        {
            int gm = m0 + r0;
            uint4 va = make_uint4(0, 0, 0, 0);
            if (gm < M) va = *(const uint4*)(A + (size_t)gm * GDIM + k0 + q * 8);
            *(uint4*)&As[r0 * 32 + q * 8] = va;
        }
#pragma unroll
        for (int p = 0; p < 2; p++) {
            int rr = r0 + p * 128;
            *(uint4*)&Bs[rr * 32 + q * 8] = *(const uint4*)(BT + (size_t)rr * GDIM + k0 + q * 8);
        }
        __syncthreads();
        bf16x8 af[4], bfr[4];
#pragma unroll
        for (int i = 0; i < 4; i++)
            af[i] = *(const bf16x8*)&As[(wm + i * 16 + lrow) * 32 + lq * 8];
#pragma unroll
        for (int j = 0; j < 4; j++)
            bfr[j] = *(const bf16x8*)&Bs[(wn + j * 16 + lrow) * 32 + lq * 8];
#pragma unroll
        for (int i = 0; i < 4; i++)
#pragma unroll
            for (int j = 0; j < 4; j++)
                acc[i][j] =
                    __builtin_amdgcn_mfma_f32_16x16x32_bf16(af[i], bfr[j], acc[i][j], 0, 0, 0);
        __syncthreads();
    }

    for (int z = tid; z < 128; z += 512) {
        rsum[z] = 0.f;
        rsq[z] = 0.f;
    }
    __syncthreads();

#pragma unroll
    for (int i = 0; i < 4; i++) {
#pragma unroll
        for (int j = 0; j < 4; j++) {
            int gn = wn + j * 16 + lrow;
            float bv = bias[gn];
#pragma unroll
            for (int r = 0; r < 4; r++) {
                int gml = wm + i * 16 + lq * 4 + r;
                int gm = m0 + gml;
                float v = fmaxf(acc[i][j][r] + bv, 0.f);
                if (gm < M) {
                    v += R[(size_t)gm * GDIM + gn];
                    C[(size_t)gm * GDIM + gn] = v;
                }
                acc[i][j][r] = v;
            }
        }
    }
#pragma unroll
    for (int i = 0; i < 4; i++) {
#pragma unroll
        for (int r = 0; r < 4; r++) {
            float s1 = 0.f, s2 = 0.f;
#pragma unroll
            for (int j = 0; j < 4; j++) {
                float v = acc[i][j][r];
                s1 += v;
                s2 += v * v;
            }
#pragma unroll
            for (int m = 1; m <= 8; m <<= 1) {
                s1 += __shfl_xor(s1, m);
                s2 += __shfl_xor(s2, m);
            }
            if (lrow == 0) {
                int rl = wm + i * 16 + lq * 4 + r;
                atomicAdd(&rsum[rl], s1);
                atomicAdd(&rsq[rl], s2);
            }
        }
    }
    __syncthreads();
#pragma unroll
    for (int i = 0; i < 4; i++) {
#pragma unroll
        for (int j = 0; j < 4; j++) {
            int gn = wn + j * 16 + lrow;
            float sc = ln_s[gn], bi = ln_b[gn];
#pragma unroll
            for (int r = 0; r < 4; r++) {
                int rl = wm + i * 16 + lq * 4 + r;
                int gm = m0 + rl;
                if (gm >= M) continue;
                float mu = rsum[rl] * (1.f / GDIM);
                float var = rsq[rl] * (1.f / GDIM) - mu * mu;
                float rstd = rsqrtf(var + 1e-5f);
                float o = (acc[i][j][r] - mu) * rstd * sc + bi;
                LNO[(size_t)gm * GDIM + gn] = f2bf(o);
            }
        }
    }
}

// ---------------- bf16 MFMA full-K, bf16 out, fused epilogue (small GEMMs) ----------------
template <int ACT, int EPI>
__global__ __launch_bounds__(256) void mfull_k(const unsigned short* __restrict__ A,
                                               const unsigned short* __restrict__ BT,
                                               const float* __restrict__ bias,
                                               const int* __restrict__ idx,
                                               const float* __restrict__ aux,
                                               unsigned short* __restrict__ O, int M, int N,
                                               int K) {
    __shared__ unsigned short As[64 * 32];
    __shared__ unsigned short Bs[64 * 32];
    int m0 = blockIdx.y * 64, n0 = blockIdx.x * 64;
    int tid = threadIdx.x;
    int wave = tid >> 6, lane = tid & 63;
    int wm = wave * 16;
    int lrow = lane & 15, lq = lane >> 4;
    f32x4 acc[4];
    const f32x4 zz = {0.f, 0.f, 0.f, 0.f};
#pragma unroll
    for (int j = 0; j < 4; j++) acc[j] = zz;
    int r0 = tid >> 2;
    int q = tid & 3;
    for (int k0 = 0; k0 < K; k0 += 32) {
        *(uint4*)&As[r0 * 32 + q * 8] = *(const uint4*)(A + (size_t)(m0 + r0) * K + k0 + q * 8);
        *(uint4*)&Bs[r0 * 32 + q * 8] = *(const uint4*)(BT + (size_t)(n0 + r0) * K + k0 + q * 8);
        __syncthreads();
        bf16x8 af = *(const bf16x8*)&As[(wm + lrow) * 32 + lq * 8];
#pragma unroll
        for (int j = 0; j < 4; j++) {
            bf16x8 bfr = *(const bf16x8*)&Bs[(j * 16 + lrow) * 32 + lq * 8];
            acc[j] = __builtin_amdgcn_mfma_f32_16x16x32_bf16(af, bfr, acc[j], 0, 0, 0);
        }
        __syncthreads();
    }
#pragma unroll
    for (int j = 0; j < 4; j++) {
        int gn = n0 + j * 16 + lrow;
        float bv = bias[gn];
#pragma unroll
        for (int r = 0; r < 4; r++) {
            int gm = m0 + wm + lq * 4 + r;
            float v = acc[j][r] + bv;
            if (ACT == 1) v = fmaxf(v, 0.f);
            if (ACT == 2) v = 0.5f * v * (1.f + erff(v * 0.70710678118654752f));
            if (EPI == 2) {
                int id = idx[gm];
                int safe = id < 0 ? 0 : id;
                v += aux[(size_t)safe * N + gn];
            }
            if (EPI == 1) {
                if (idx[gm] < 0) v = aux[gn];
            }
            O[(size_t)gm * N + gn] = f2bf(v);
        }
    }
}

// ---------------- bf16 MFMA split-K phase 1: 64x64 tile, fp32 partials ----------------
__global__ __launch_bounds__(256) void msk_k(const unsigned short* __restrict__ A,
                                             const unsigned short* __restrict__ BT,
                                             float* __restrict__ Cp, int M, int N, int K,
                                             int kchunk) {
    __shared__ unsigned short As[64 * 32];
    __shared__ unsigned short Bs[64 * 32];
    int m0 = blockIdx.y * 64, n0 = blockIdx.x * 64;
    int kbeg = blockIdx.z * kchunk;
    float* C = Cp + (size_t)blockIdx.z * M * N;
    int tid = threadIdx.x;
    int wave = tid >> 6, lane = tid & 63;
    int wm = wave * 16;
    int lrow = lane & 15, lq = lane >> 4;
    f32x4 acc[4];
    const f32x4 zz = {0.f, 0.f, 0.f, 0.f};
#pragma unroll
    for (int j = 0; j < 4; j++) acc[j] = zz;
    int r0 = tid >> 2;
    int q = tid & 3;
    for (int k0 = kbeg; k0 < kbeg + kchunk; k0 += 32) {
        *(uint4*)&As[r0 * 32 + q * 8] = *(const uint4*)(A + (size_t)(m0 + r0) * K + k0 + q * 8);
        *(uint4*)&Bs[r0 * 32 + q * 8] = *(const uint4*)(BT + (size_t)(n0 + r0) * K + k0 + q * 8);
        __syncthreads();
        bf16x8 af = *(const bf16x8*)&As[(wm + lrow) * 32 + lq * 8];
#pragma unroll
        for (int j = 0; j < 4; j++) {
            bf16x8 bfr = *(const bf16x8*)&Bs[(j * 16 + lrow) * 32 + lq * 8];
            acc[j] = __builtin_amdgcn_mfma_f32_16x16x32_bf16(af, bfr, acc[j], 0, 0, 0);
        }
        __syncthreads();
    }
#pragma unroll
    for (int j = 0; j < 4; j++) {
        int gn = n0 + j * 16 + lrow;
#pragma unroll
        for (int r = 0; r < 4; r++) {
            int gm = m0 + wm + lq * 4 + r;
            C[(size_t)gm * N + gn] = acc[j][r];
        }
    }
}

// ---------------- fused reducer (head, M=256, N=512) ----------------
template <bool RESID, bool DO_LN>
__global__ void redln_k(const float* __restrict__ Cp, const float* __restrict__ bias,
                        const float* __restrict__ ln_s, const float* __restrict__ ln_b,
                        float* __restrict__ hbuf, unsigned short* __restrict__ outbf, int S) {
    int row = blockIdx.x * 4 + (threadIdx.x >> 6);
    int lane = threadIdx.x & 63;
    float4 a0 = {0.f, 0.f, 0.f, 0.f}, a1 = a0;
    for (int s = 0; s < S; s++) {
        const float4* pp = (const float4*)(Cp + ((size_t)s * BSZ + row) * HID);
        float4 b0 = pp[lane * 2], b1 = pp[lane * 2 + 1];
        a0.x += b0.x; a0.y += b0.y; a0.z += b0.z; a0.w += b0.w;
        a1.x += b1.x; a1.y += b1.y; a1.z += b1.z; a1.w += b1.w;
    }
    const float4* bb = (const float4*)bias;
    float4 c0 = bb[lane * 2], c1 = bb[lane * 2 + 1];
    a0.x += c0.x; a0.y += c0.y; a0.z += c0.z; a0.w += c0.w;
    a1.x += c1.x; a1.y += c1.y; a1.z += c1.z; a1.w += c1.w;
    float4* hp = (float4*)(hbuf + (size_t)row * HID);
    if (RESID) {
        float4 r0 = hp[lane * 2], r1 = hp[lane * 2 + 1];
        a0.x += r0.x; a0.y += r0.y; a0.z += r0.z; a0.w += r0.w;
        a1.x += r1.x; a1.y += r1.y; a1.z += r1.z; a1.w += r1.w;
    }
    hp[lane * 2] = a0;
    hp[lane * 2 + 1] = a1;
    unsigned short* op = outbf + (size_t)row * HID;
    if (DO_LN) {
        float sum = a0.x + a0.y + a0.z + a0.w + a1.x + a1.y + a1.z + a1.w;
#pragma unroll
        for (int off = 32; off >= 1; off >>= 1) sum += __shfl_xor(sum, off);
        float mu = sum / HID;
        float d0 = a0.x - mu, d1 = a0.y - mu, d2 = a0.z - mu, d3 = a0.w - mu;
        float d4 = a1.x - mu, d5 = a1.y - mu, d6 = a1.z - mu, d7 = a1.w - mu;
        float sq = d0 * d0 + d1 * d1 + d2 * d2 + d3 * d3 + d4 * d4 + d5 * d5 + d6 * d6 + d7 * d7;
#pragma unroll
        for (int off = 32; off >= 1; off >>= 1) sq += __shfl_xor(sq, off);
        float rstd = rsqrtf(sq / HID + 1e-5f);
        const float4* sp = (const float4*)ln_s;
        const float4* bp = (const float4*)ln_b;
        float4 s0 = sp[lane * 2], s1 = sp[lane * 2 + 1];
        float4 t0 = bp[lane * 2], t1 = bp[lane * 2 + 1];
        *(ushort4*)(op + lane * 8) =
            make_ushort4(f2bf(d0 * rstd * s0.x + t0.x), f2bf(d1 * rstd * s0.y + t0.y),
                         f2bf(d2 * rstd * s0.z + t0.z), f2bf(d3 * rstd * s0.w + t0.w));
        *(ushort4*)(op + lane * 8 + 4) =
            make_ushort4(f2bf(d4 * rstd * s1.x + t1.x), f2bf(d5 * rstd * s1.y + t1.y),
                         f2bf(d6 * rstd * s1.z + t1.z), f2bf(d7 * rstd * s1.w + t1.w));
    } else {
        *(ushort4*)(op + lane * 8) = make_ushort4(f2bf(a0.x), f2bf(a0.y), f2bf(a0.z), f2bf(a0.w));
        *(ushort4*)(op + lane * 8 + 4) =
            make_ushort4(f2bf(a1.x), f2bf(a1.y), f2bf(a1.z), f2bf(a1.w));
    }
}

// ---------------- bf16 MFMA GEMM 128x128 (logits) ----------------
template <int ACT, bool RES, bool BIAS>
__global__ __launch_bounds__(256) void mgemm_k(const unsigned short* __restrict__ A,
                                               const unsigned short* __restrict__ BT,
                                               const float* __restrict__ bias,
                                               const float* __restrict__ R,
                                               float* __restrict__ C, int M, int N, int K) {
    __shared__ unsigned short As[128 * 32];
    __shared__ unsigned short Bs[128 * 32];
    int m0 = blockIdx.y * 128, n0 = blockIdx.x * 128;
    int tid = threadIdx.x;
    int wave = tid >> 6, lane = tid & 63;
    int wm = (wave >> 1) * 64, wn = (wave & 1) * 64;
    int lrow = lane & 15, lq = lane >> 4;

    f32x4 acc[4][4];
    const f32x4 zz = {0.f, 0.f, 0.f, 0.f};
#pragma unroll
    for (int i = 0; i < 4; i++)
#pragma unroll
        for (int j = 0; j < 4; j++) acc[i][j] = zz;

    int r0 = tid >> 2;
    int q = tid & 3;

    for (int k0 = 0; k0 < K; k0 += 32) {
#pragma unroll
        for (int p = 0; p < 2; p++) {
            int row = r0 + p * 64;
            int gm = m0 + row;
            uint4 va = make_uint4(0, 0, 0, 0);
            if (gm < M) va = *(const uint4*)(A + (size_t)gm * K + k0 + q * 8);
            *(uint4*)&As[row * 32 + q * 8] = va;
            int gn = n0 + row;
            uint4 vb = make_uint4(0, 0, 0, 0);
            if (gn < N) vb = *(const uint4*)(BT + (size_t)gn * K + k0 + q * 8);
            *(uint4*)&Bs[row * 32 + q * 8] = vb;
        }
        __syncthreads();
        bf16x8 af[4], bfr[4];
#pragma unroll
        for (int i = 0; i < 4; i++)
            af[i] = *(const bf16x8*)&As[(wm + i * 16 + lrow) * 32 + lq * 8];
#pragma unroll
        for (int j = 0; j < 4; j++)
            bfr[j] = *(const bf16x8*)&Bs[(wn + j * 16 + lrow) * 32 + lq * 8];
#pragma unroll
        for (int i = 0; i < 4; i++)
#pragma unroll
            for (int j = 0; j < 4; j++)
                acc[i][j] =
                    __builtin_amdgcn_mfma_f32_16x16x32_bf16(af[i], bfr[j], acc[i][j], 0, 0, 0);
        __syncthreads();
    }

#pragma unroll
    for (int i = 0; i < 4; i++) {
#pragma unroll
        for (int j = 0; j < 4; j++) {
            int gn = n0 + wn + j * 16 + lrow;
            if (gn >= N) continue;
            float bv = BIAS ? bias[gn] : 0.f;
#pragma unroll
            for (int r = 0; r < 4; r++) {
                int gm = m0 + wm + i * 16 + lq * 4 + r;
                if (gm >= M) continue;
                float v = acc[i][j][r] + bv;
                if (ACT == 1) v = fmaxf(v, 0.f);
                if (RES) v += R[(size_t)gm * N + gn];
                C[(size_t)gm * N + gn] = v;
            }
        }
    }
}

// ---------------- launch ----------------
extern "C" void kernel_launch(void* const* d_in, const int* in_sizes, int n_in,
                              void* d_out, int out_size, void* d_ws, size_t ws_size,
                              hipStream_t stream) {
    const int* node_indices = (const int*)d_in[0];
    const int* edge_src = (const int*)d_in[1];
    const int* edge_dst = edge_src + NEDGES;
    const float* edge_w = (const float*)d_in[2];
    const float* partial_emb = (const float*)d_in[3];
    const float* oov_emb = (const float*)d_in[4];
    const float* gnn_ln_s = (const float*)d_in[5];
    const float* gnn_ln_b = (const float*)d_in[6];
    const float* gnn_w = (const float*)d_in[7];
    const float* gnn_b = (const float*)d_in[8];
    const float* post_w = (const float*)d_in[9];
    const float* post_b = (const float*)d_in[10];
    const float* pin_w = (const float*)d_in[11];
    const float* pin_b = (const float*)d_in[12];
    const float* blk_ln_s = (const float*)d_in[13];
    const float* blk_ln_b = (const float*)d_in[14];
    const float* blk_w1 = (const float*)d_in[15];
    const float* blk_b1 = (const float*)d_in[16];
    const float* blk_w2 = (const float*)d_in[17];
    const float* blk_b2 = (const float*)d_in[18];
    const float* pout_w = (const float*)d_in[19];
    const float* pout_b = (const float*)d_in[20];
    const float* gene = (const float*)d_in[21];
    float* out = (float*)d_out;

    char* p = (char*)d_ws;
    auto alloc = [&](size_t bytes) {
        char* r = p;
        p += (bytes + 255) & ~(size_t)255;
        return r;
    };
    int* counts = (int*)alloc(NNODES * 4);
    int* row_start = (int*)alloc(NNODES * 4);
    int* cursor = (int*)alloc(NNODES * 4);
    int2* epack = (int2*)alloc((size_t)NEDGES * 8);
    // 'part': GNN phase = ln_bf + aggbf (bf16); head phase = split-K fp32 partials
    float* part = (float*)alloc((size_t)NNODES * GDIM * 4);
    unsigned short* ln_bf = (unsigned short*)part;
    unsigned short* aggbf = (unsigned short*)((char*)part + (size_t)NNODES * GDIM * 2);
    float* xa = (float*)alloc((size_t)NNODES * GDIM * 4);
    float* xb = (float*)alloc((size_t)NNODES * GDIM * 4);
    float* hbuf = (float*)alloc((size_t)BSZ * HID * 4);
    unsigned short* aggselb = (unsigned short*)alloc((size_t)BSZ * GDIM * 2);
    unsigned short* pertinbf = (unsigned short*)alloc((size_t)BSZ * GDIM * 2);
    unsigned short* pertbf = (unsigned short*)alloc((size_t)BSZ * GDIM * 2);
    unsigned short* zlnbf = (unsigned short*)alloc((size_t)BSZ * HID * 2);
    unsigned short* z1bf = (unsigned short*)alloc((size_t)BSZ * INNER * 2);
    unsigned short* hbufbf = (unsigned short*)alloc((size_t)BSZ * HID * 2);
    unsigned short* projb = (unsigned short*)alloc((size_t)BSZ * NCLS * RANK * 2);
    unsigned short* gnnT = (unsigned short*)alloc((size_t)3 * GDIM * GDIM * 2);
    unsigned short* postT = (unsigned short*)alloc((size_t)GDIM * GDIM * 2);
    unsigned short* pinT = (unsigned short*)alloc((size_t)HID * GDIM * 2);
    unsigned short* w1T = (unsigned short*)alloc((size_t)6 * INNER * HID * 2);
    unsigned short* w2T = (unsigned short*)alloc((size_t)6 * HID * INNER * 2);
    unsigned short* poutT = (unsigned short*)alloc((size_t)NCLS * RANK * HID * 2);
    unsigned short* geneb = (unsigned short*)alloc((size_t)NGENES * RANK * 2);

    const int EB = (NEDGES + 255) / 256;

    hipMemsetAsync(counts, 0, NNODES * 4, stream);
    convall_k<<<15100, dim3(32, 8), 0, stream>>>(gnn_w, post_w, pin_w, blk_w1, blk_w2, pout_w,
                                                 gene, gnnT, postT, pinT, w1T, w2T, poutT, geneb);

    // CSR build
    hist_k<<<EB, 256, 0, stream>>>(edge_dst, counts, NEDGES);
    scanall_k<<<1, 1024, 0, stream>>>(counts, row_start, cursor, NNODES);
    scatter_k<<<EB, 256, 0, stream>>>(edge_src, edge_dst, edge_w, cursor, epack, NEDGES);

    // GNN: L1 lnb, L1/L2 GEMM+LN fused, L3 selective
    lnb_k<<<(NNODES + 3) / 4, 256, 0, stream>>>(partial_emb, gnn_ln_s, gnn_ln_b, ln_bf, NNODES);
    aggb_k<<<(NNODES + 3) / 4, 256, 0, stream>>>(row_start, counts, epack, ln_bf, aggbf, NNODES);
    mgemmln_k<<<(NNODES + 127) / 128, 512, 0, stream>>>(
        aggbf, gnnT, gnn_b, partial_emb, gnn_ln_s + GDIM, gnn_ln_b + GDIM, xa, ln_bf, NNODES);
    aggb_k<<<(NNODES + 3) / 4, 256, 0, stream>>>(row_start, counts, epack, ln_bf, aggbf, NNODES);
    mgemmln_k<<<(NNODES + 127) / 128, 512, 0, stream>>>(
        aggbf, gnnT + (size_t)GDIM * GDIM, gnn_b + GDIM, xa, gnn_ln_s + 2 * GDIM,
        gnn_ln_b + 2 * GDIM, xb, ln_bf, NNODES);
    aggsel_k<<<BSZ / 4, 256, 0, stream>>>(node_indices, row_start, counts, epack, ln_bf, aggselb);
    mfull_k<1, 2><<<dim3(GDIM / 64, BSZ / 64), 256, 0, stream>>>(
        aggselb, gnnT + (size_t)2 * GDIM * GDIM, gnn_b + 2 * GDIM, node_indices, xb, pertinbf,
        BSZ, GDIM, GDIM);

    // post_mp + OOV replace
    mfull_k<0, 1><<<dim3(GDIM / 64, BSZ / 64), 256, 0, stream>>>(
        pertinbf, postT, post_b, node_indices, oov_emb, pertbf, BSZ, GDIM, GDIM);

    // pin (split-K S=4 + fused reduce/LN)
    msk_k<<<dim3(HID / 64, BSZ / 64, 4), 256, 0, stream>>>(pertbf, pinT, part, BSZ, HID, GDIM,
                                                           GDIM / 4);
    redln_k<false, true><<<BSZ / 4, 256, 0, stream>>>(part, pin_b, blk_ln_s, blk_ln_b, hbuf,
                                                      zlnbf, 4);

    // 6 head blocks
    for (int i = 0; i < 6; i++) {
        mfull_k<2, 0><<<dim3(INNER / 64, BSZ / 64), 256, 0, stream>>>(
            zlnbf, w1T + (size_t)i * INNER * HID, blk_b1 + i * INNER, nullptr, nullptr, z1bf, BSZ,
            INNER, HID);
        msk_k<<<dim3(HID / 64, BSZ / 64, 8), 256, 0, stream>>>(
            z1bf, w2T + (size_t)i * HID * INNER, part, BSZ, HID, INNER, INNER / 8);
        if (i < 5) {
            redln_k<true, true><<<BSZ / 4, 256, 0, stream>>>(
                part, blk_b2 + i * HID, blk_ln_s + (i + 1) * HID, blk_ln_b + (i + 1) * HID, hbuf,
                zlnbf, 8);
        } else {
            redln_k<true, false><<<BSZ / 4, 256, 0, stream>>>(part, blk_b2 + i * HID, nullptr,
                                                              nullptr, hbuf, hbufbf, 8);
        }
    }

    // pout
    mfull_k<0, 0><<<dim3((NCLS * RANK) / 64, BSZ / 64), 256, 0, stream>>>(
        hbufbf, poutT, pout_b, nullptr, nullptr, projb, BSZ, NCLS * RANK, HID);

    // logits
    mgemm_k<0, false, false><<<dim3((NGENES + 127) / 128, (BSZ * NCLS) / 128), 256, 0, stream>>>(
        projb, geneb, nullptr, nullptr, out, BSZ * NCLS, NGENES, RANK);
}